// Round 22
// baseline (7465.060 us; speedup 1.0000x reference)
//
#include <hip/hip_runtime.h>
#include <hip/hip_bf16.h>
#include <stdint.h>

// Problem constants (fixed by the reference): T=512, B=64, IN=H=1024, L=2
#define TT 512
#define BB 64
#define HH 1024
#define BH 65536    // B*H elements
#define KD 2048     // IN+H == H+H

typedef __attribute__((ext_vector_type(8))) short short8;
typedef __attribute__((ext_vector_type(4))) float f32x4;

__device__ __forceinline__ unsigned short f2bf(float f) {
  union { float f; unsigned int u; } v; v.f = f;
  unsigned int r = v.u + 0x7fffu + ((v.u >> 16) & 1u);  // RNE
  return (unsigned short)(r >> 16);
}
__device__ __forceinline__ float bf2f(unsigned short u) {
  union { unsigned int u; float f; } v; v.u = ((unsigned int)u) << 16; return v.f;
}
__device__ __forceinline__ float fsig(float x)  { return 1.0f / (1.0f + __expf(-x)); }
__device__ __forceinline__ float ftanhf(float x){ return 1.0f - 2.0f / (__expf(2.0f * x) + 1.0f); }

// ---------------- x -> bf16 (row-major) ----------------
__global__ void cvt_x_kernel(const float* __restrict__ x, unsigned short* __restrict__ xbf) {
  const int n4 = (TT * BB * 1024) / 4;
  int stride = gridDim.x * blockDim.x;
  for (int i = blockIdx.x * blockDim.x + threadIdx.x; i < n4; i += stride) {
    float4 v = ((const float4*)x)[i];
    unsigned long long p = (unsigned long long)f2bf(v.x)
        | ((unsigned long long)f2bf(v.y) << 16)
        | ((unsigned long long)f2bf(v.z) << 32)
        | ((unsigned long long)f2bf(v.w) << 48);
    ((unsigned long long*)xbf)[i] = p;
  }
}

// ---------------- W [4096][2048] f32 -> bf16, LDS-image layout (TRANSPOSED-C perm) ----
// Ws[g][kk 0..63][nrow 0..31][hi 0..3][8 bf16]; nrow: nt=nrow>>4, q=nrow&3, jl=(nrow>>2)&3
//   -> W row = q*1024 + g*8 + nt*4 + jl ; kk<32: k=kk*32+hi*8 ; kk>=32: k=1024+(kk-32)*32+hi*8
__global__ void cvt_w_kernel(const float* __restrict__ W, unsigned short* __restrict__ Ws) {
  int idx = blockIdx.x * blockDim.x + threadIdx.x;   // < 1,048,576
  int hi = idx & 3;
  int nr = (idx >> 2) & 31;
  int kk = (idx >> 7) & 63;
  int g  = idx >> 13;
  int q  = nr & 3;
  int jl = (nr >> 2) & 3;
  int nt = nr >> 4;
  int grow = (q << 10) + (g << 3) + (nt << 2) + jl;
  int k = ((kk < 32) ? (kk << 5) : (1024 + ((kk - 32) << 5))) + (hi << 3);
  const float* src = W + (size_t)grow * KD + k;
  float4 v0 = ((const float4*)src)[0];
  float4 v1 = ((const float4*)src)[1];
  unsigned long long p0 = (unsigned long long)f2bf(v0.x)
      | ((unsigned long long)f2bf(v0.y) << 16)
      | ((unsigned long long)f2bf(v0.z) << 32)
      | ((unsigned long long)f2bf(v0.w) << 48);
  unsigned long long p1 = (unsigned long long)f2bf(v1.x)
      | ((unsigned long long)f2bf(v1.y) << 16)
      | ((unsigned long long)f2bf(v1.z) << 32)
      | ((unsigned long long)f2bf(v1.w) << 48);
  unsigned long long* dst = (unsigned long long*)(Ws + ((size_t)g << 16) + (kk << 10) + (nr << 5) + (hi << 3));
  dst[0] = p0;
  dst[1] = p1;
}

// ---------------- initial h -> hist slot 0 (BLOCKED layout [cb][m][8]) ----------------
__global__ void init_state_kernel(const float* __restrict__ h0in,
                                  unsigned short* h0s0, unsigned short* h1s0) {
  int i = blockIdx.x * blockDim.x + threadIdx.x;  // < BH
  int m = i >> 10, c = i & 1023;
  int dst = ((c >> 3) << 9) + (m << 3) + (c & 7);
  h0s0[dst] = f2bf(h0in[i]);
  h1s0[dst] = f2bf(h0in[BH + i]);
}

// ---------------- post-pass: blocked bf16 hist -> row-major fp32 out ----------------
__global__ void finalize_kernel(const unsigned short* __restrict__ h0hist,
                                const unsigned short* __restrict__ h1hist,
                                float* __restrict__ out) {
  const size_t NCH = (size_t)(TT + 2) * (BH / 8);
  size_t stride = (size_t)gridDim.x * blockDim.x;
  for (size_t i = (size_t)blockIdx.x * blockDim.x + threadIdx.x; i < NCH; i += stride) {
    int p  = (int)(i >> 13);     // BH/8 = 8192
    int ci = (int)(i & 8191);
    int cb = ci >> 6, m = ci & 63;
    const unsigned short* src;
    size_t dbase;
    if (p < TT)       { src = h1hist + (size_t)(p + 1) * BH; dbase = (size_t)p * BH; }
    else if (p == TT) { src = h0hist + (size_t)TT * BH;      dbase = (size_t)TT * BH; }
    else              { src = h1hist + (size_t)TT * BH;      dbase = (size_t)TT * BH + BH; }
    const unsigned short* sp = src + ((size_t)ci << 3);
    ushort4 v0 = ((const ushort4*)sp)[0];
    ushort4 v1 = ((const ushort4*)sp)[1];
    float* dp = out + dbase + (m << 10) + (cb << 3);
    *(float4*)(dp)     = make_float4(bf2f(v0.x), bf2f(v0.y), bf2f(v0.z), bf2f(v0.w));
    *(float4*)(dp + 4) = make_float4(bf2f(v1.x), bf2f(v1.y), bf2f(v1.z), bf2f(v1.w));
  }
}

#define GLD(p)    __hip_atomic_load((p),  __ATOMIC_RELAXED, __HIP_MEMORY_SCOPE_AGENT)
#define GST(p, v) __hip_atomic_store((p), (v), __ATOMIC_RELAXED, __HIP_MEMORY_SCOPE_AGENT)

// spin until the 8 sub-counters (256B apart) sum to 128
__device__ __forceinline__ void poll128(int* base) {
  for (;;) {
    int s = 0;
#pragma unroll
    for (int j = 0; j < 8; j++)
      s += GLD(base + (j << 6));
    if (s >= 128) return;
    __builtin_amdgcn_s_sleep(1);
  }
}

// ---------------- persistent 2-layer LSTM, v17: barrier-free self-paced mt-convoys ----
// 256 blocks; waves 4-7 exit after weight staging -> 4 compute waves/block, one
// per m-tile. Blocks 0-127: layer0, 128-255: layer1. TRANSPOSED MFMA, lane-local
// epilogue, BLOCKED h hist (full-line sc1 stores).
// NO A/B split, NO pbuf, NO in-loop barriers. Each wave computes the full cell
// for its (mt, 2 n-tiles): SA stream (L0: x[s]; L1: h0hist[s+1]) + SB stream
// (own-layer h[s]), 128 MFMAs in strict kk order 0..63 (FP sum order == r18:
// absmax is the race canary). SA loads ISSUE BEFORE the tight SB poll (latency
// hides under the wait). Sync: per-(s,mt) MONOTONE split counters; publisher =
// wave lane0 atomicAdd after its OWN s_waitcnt vmcnt(0); consumer wave polls
// only its own mt. Monotone + full write-once history -> L0 free-runs ahead
// unboundedly; L1's SA gate (cnt0m[s][mt]) is then always already satisfied.
// Convoy granularity: per (layer, mt) only -- no intra-block coupling at all.
__global__ __launch_bounds__(512, 2) void lstm_persist(
    const unsigned short* __restrict__ W0s, const unsigned short* __restrict__ W1s,
    const float* __restrict__ b0, const float* __restrict__ b1,
    const unsigned short* __restrict__ xbf,
    unsigned short* h0hist, unsigned short* h1hist,
    const float* __restrict__ c0in, float* out, int* cnt0m, int* cnt1m)
{
  __shared__ short8 wlds[8192];            // 128 KB: [kk 0..63][nrow 0..31][hi 0..3]
  const int tid = threadIdx.x;
  const int bid = blockIdx.x;
  const int layer = bid >> 7;
  const int g = bid & 127;

  const unsigned short* Ws = layer ? W1s : W0s;
  const float* bias = layer ? b1 : b0;

  // ---- stage weight slice once: linear 128KB copy (all 8 waves) ----
  {
    const short8* wsrc = (const short8*)(Ws + ((size_t)g << 16));
#pragma unroll
    for (int it = 0; it < 16; it++)
      wlds[tid + (it << 9)] = wsrc[tid + (it << 9)];
  }
  __syncthreads();   // weights staged (only barrier in the kernel)
  const int w = tid >> 6;
  if (w >= 4) return;   // waves 4-7 done

  // ---- wave / lane mapping ----
  const int lane = tid & 63;
  const int mt = w;               // m-tile (batch)
  const int m0 = mt << 4;
  const int n  = lane & 15;       // batch row within tile (C column)
  const int hi = lane >> 4;       // k-subchunk for operands; h-col within 4 for C
  const short8* bbase0 = wlds + ((n << 2) + hi);          // n-tile 0 rows 0..15
  const short8* bbase1 = wlds + (((16 + n) << 2) + hi);   // n-tile 1 rows 16..31
  const int m = m0 + n;                                   // this lane's batch row
  const int rowoff = (m << 10) + (hi << 3);               // x row base (row-major)
  const int bro = ((hi << 6) + m) << 3;                   // blocked h base: frag kk at bro + kk*2048
  const int col0 = (g << 3) + hi;                         // h-col, n-tile 0
  const int col1 = col0 + 4;                              // h-col, n-tile 1

  unsigned short* const myhist = layer ? h1hist : h0hist;
  int* const mycnt = layer ? cnt1m : cnt0m;
  const unsigned short* const SAall = layer ? (h0hist + (size_t)BH) : xbf;  // L1 SA: h0hist[s+1]
  const int SAoff = layer ? bro : rowoff;
  const int sash  = layer ? 11 : 5;       // SA fragment stride (elements): blocked vs row-major

  // ---- per-lane gate biases + c registers (both n-tiles) ----
  float bq[2][4];
  float creg[2];
#pragma unroll
  for (int nt2 = 0; nt2 < 2; nt2++) {
    int col = nt2 ? col1 : col0;
#pragma unroll
    for (int qg = 0; qg < 4; qg++)
      bq[nt2][qg] = bias[(qg << 10) + col];
    creg[nt2] = c0in[(size_t)layer * BH + (m << 10) + col];
  }

  for (int s = 0; s < TT; s++) {
    // ---- SA gate (L1 only; L0 free-runs so this is nearly always satisfied) ----
    if (layer) {
      if (lane == 0) poll128(cnt0m + (((s << 2) + mt) << 9));
      asm volatile("" ::: "memory");
    }
    // ---- issue SA loads (dependency-free / early-gated) BEFORE the tight poll ----
    const unsigned short* SA = SAall + (size_t)s * BH + SAoff;
    short8 sa[16];
#pragma unroll
    for (int j = 0; j < 16; j++) sa[j] = *(const short8*)(SA + (j << sash));

    // ---- SB tight gate: own-layer recurrence (per-mt monotone counter) ----
    if (s >= 1) {
      if (lane == 0) poll128(mycnt + ((((s - 1) << 2) + mt) << 9));
      asm volatile("" ::: "memory");   // no SB-load hoisting above the spin
    }
    const unsigned short* SB = myhist + (size_t)s * BH + bro;
    short8 sb[16], sc[16];
#pragma unroll
    for (int j = 0; j < 16; j++) sb[j] = *(const short8*)(SB + (j << 11));
#pragma unroll
    for (int j = 0; j < 16; j++) sc[j] = *(const short8*)(SB + ((16 + j) << 11));

    // ---- full-cell GEMM, strict kk order 0..63 (== r18 summation order) ----
    f32x4 acc0 = {0.f, 0.f, 0.f, 0.f}, acc1 = {0.f, 0.f, 0.f, 0.f};
#pragma unroll
    for (int j = 0; j < 16; j++) {
      acc0 = __builtin_amdgcn_mfma_f32_16x16x32_bf16(bbase0[j << 7], sa[j], acc0, 0, 0, 0);
      acc1 = __builtin_amdgcn_mfma_f32_16x16x32_bf16(bbase1[j << 7], sa[j], acc1, 0, 0, 0);
      sa[j] = *(const short8*)(SA + ((16 + j) << sash));
    }
#pragma unroll
    for (int j = 0; j < 16; j++) {
      acc0 = __builtin_amdgcn_mfma_f32_16x16x32_bf16(bbase0[(16 + j) << 7], sa[j], acc0, 0, 0, 0);
      acc1 = __builtin_amdgcn_mfma_f32_16x16x32_bf16(bbase1[(16 + j) << 7], sa[j], acc1, 0, 0, 0);
    }
#pragma unroll
    for (int j = 0; j < 16; j++) {
      acc0 = __builtin_amdgcn_mfma_f32_16x16x32_bf16(bbase0[(32 + j) << 7], sb[j], acc0, 0, 0, 0);
      acc1 = __builtin_amdgcn_mfma_f32_16x16x32_bf16(bbase1[(32 + j) << 7], sb[j], acc1, 0, 0, 0);
    }
#pragma unroll
    for (int j = 0; j < 16; j++) {
      acc0 = __builtin_amdgcn_mfma_f32_16x16x32_bf16(bbase0[(48 + j) << 7], sc[j], acc0, 0, 0, 0);
      acc1 = __builtin_amdgcn_mfma_f32_16x16x32_bf16(bbase1[(48 + j) << 7], sc[j], acc1, 0, 0, 0);
    }

    // ---- epilogue: LANE-LOCAL cell update; blocked full-line sc1 h-stores ----
    unsigned short* hbb = myhist + (size_t)(s + 1) * BH + (((g << 6) + m) << 3);
#pragma unroll
    for (int nt2 = 0; nt2 < 2; nt2++) {
      f32x4 acc = nt2 ? acc1 : acc0;
      float ig = fsig(acc[0] + bq[nt2][0]);
      float fg = fsig(acc[1] + bq[nt2][1]);
      float gg = ftanhf(acc[2] + bq[nt2][2]);
      float og = fsig(acc[3] + bq[nt2][3]);
      float cn = ig * gg + fg * creg[nt2];
      float hn = og * ftanhf(cn);
      creg[nt2] = cn;
      GST(hbb + (nt2 << 2) + hi, f2bf(hn));
    }

    // ---- publish: own-wave drain, then ONE atomicAdd to per-(s,mt) counter ----
    asm volatile("s_waitcnt vmcnt(0)" ::: "memory");
    if (lane == 0)
      atomicAdd(mycnt + (((s << 2) + mt) << 9) + ((g & 7) << 6), 1);

    // ---- final c (once, off the per-step path) ----
    if (s == TT - 1) {
#pragma unroll
      for (int nt2 = 0; nt2 < 2; nt2++) {
        const int col = nt2 ? col1 : col0;
        out[(size_t)TT * BH + (size_t)(2 + layer) * BH + (m << 10) + col] = creg[nt2];
      }
    }
  }
}

extern "C" void kernel_launch(void* const* d_in, const int* in_sizes, int n_in,
                              void* d_out, int out_size, void* d_ws, size_t ws_size,
                              hipStream_t stream) {
  (void)in_sizes; (void)n_in; (void)out_size; (void)ws_size;
  const float* x    = (const float*)d_in[0];
  const float* h0in = (const float*)d_in[1];
  const float* c0in = (const float*)d_in[2];
  const float* W0   = (const float*)d_in[3];
  const float* b0   = (const float*)d_in[4];
  const float* W1   = (const float*)d_in[5];
  const float* b1   = (const float*)d_in[6];
  float* out = (float*)d_out;

  char* ws = (char*)d_ws;
  const size_t HIST = (size_t)(TT + 1) * BH * sizeof(unsigned short);  // 67,239,936 B
  unsigned short* Xbf    = (unsigned short*)(ws);                      // 64 MB
  unsigned short* W0s    = (unsigned short*)(ws + 67108864);           // 16 MB
  unsigned short* W1s    = (unsigned short*)(ws + 83886080);           // 16 MB
  unsigned short* h0hist = (unsigned short*)(ws + 100663296);          // 64.1 MB
  unsigned short* h1hist = (unsigned short*)(ws + 100663296 + HIST);   // 64.1 MB
  int* cnt0m             = (int*)(ws + 100663296 + 2 * HIST);          // 4 MB
  int* cnt1m             = cnt0m + (1 << 20);                          // 4 MB

  hipMemsetAsync(cnt0m, 0, (size_t)8 << 20, stream);
  cvt_x_kernel<<<2048, 256, 0, stream>>>(x, Xbf);
  cvt_w_kernel<<<4096, 256, 0, stream>>>(W0, W0s);
  cvt_w_kernel<<<4096, 256, 0, stream>>>(W1, W1s);
  init_state_kernel<<<256, 256, 0, stream>>>(h0in, h0hist, h1hist);

  lstm_persist<<<256, 512, 0, stream>>>(W0s, W1s, b0, b1, Xbf,
                                        h0hist, h1hist, c0in, out, cnt0m, cnt1m);

  finalize_kernel<<<2048, 256, 0, stream>>>(h0hist, h1hist, out);
}